// Round 1
// baseline (498.381 us; speedup 1.0000x reference)
//
#include <hip/hip_runtime.h>

#define HH   112
#define WW   320
#define CIN_ 128
#define TILE 8            // pixels per 256-thread block (2 per wave)

__device__ __forceinline__ float lrelu(float v) {
    return v >= 0.f ? v : 0.01f * v;
}

__global__ __launch_bounds__(256, 4)
void reg3_fused(const float* __restrict__ x_in,
                const float* __restrict__ w1_0, const float* __restrict__ b1_0,
                const float* __restrict__ w1_1, const float* __restrict__ b1_1,
                const float* __restrict__ w1_2, const float* __restrict__ b1_2,
                const float* __restrict__ w2_0, const float* __restrict__ b2_0,
                const float* __restrict__ w2_1, const float* __restrict__ b2_1,
                const float* __restrict__ w2_2, const float* __restrict__ b2_2,
                const float* __restrict__ w3_0, const float* __restrict__ b3_0,
                const float* __restrict__ w3_1, const float* __restrict__ b3_1,
                const float* __restrict__ w3_2, const float* __restrict__ b3_2,
                int* __restrict__ out)
{
    __shared__ float xT[TILE][CIN_ + 1];      // +1 pad: conflict-free
    __shared__ float w1s0[32][CIN_ + 1];
    __shared__ float w1s1[32][33];
    __shared__ float w1s2[16][33];
    __shared__ float b1s[80];                 // [0,32)=b1_0  [32,64)=b1_1  [64,80)=b1_2

    const int tilesPerLine = WW / TILE;       // 40
    const int h   = blockIdx.x / tilesPerLine;
    const int w0  = (blockIdx.x % tilesPerLine) * TILE;
    const int tid = threadIdx.x;

    // stage x rows (transposed) into LDS
    for (int n = tid; n < TILE * CIN_; n += 256) {
        int ww = n % TILE, c = n / TILE;
        xT[ww][c] = x_in[c * (HH * WW) + h * WW + w0 + ww];
    }
    // stage per-line stage-1 weights into LDS (coalesced global reads)
    for (int n = tid; n < 32 * CIN_; n += 256)
        w1s0[n >> 7][n & 127] = w1_0[h * (32 * CIN_) + n];
    for (int n = tid; n < 32 * 32; n += 256)
        w1s1[n >> 5][n & 31] = w1_1[h * (32 * 32) + n];
    for (int n = tid; n < 16 * 32; n += 256)
        w1s2[n >> 5][n & 31] = w1_2[h * (16 * 32) + n];
    if      (tid < 32) b1s[tid] = b1_0[h * 32 + tid];
    else if (tid < 64) b1s[tid] = b1_1[h * 32 + (tid - 32)];
    else if (tid < 80) b1s[tid] = b1_2[h * 16 + (tid - 64)];
    __syncthreads();

    const int wave = tid >> 6;
    const int lane = tid & 63;
    const int o    = lane & 31;
    const int half = lane >> 5;
    const int o16  = lane & 15;

    for (int p = 0; p < TILE / 4; ++p) {
        const int pix = wave * (TILE / 4) + p;
        const float* xr = &xT[pix][0];

        // ================= stage 1 (per-line weights, LDS) =================
        float acc = 0.f;
        #pragma unroll 8
        for (int i = 0; i < 64; ++i) {
            int ii = half * 64 + i;
            acc += xr[ii] * w1s0[o][ii];
        }
        acc += __shfl_xor(acc, 32);
        float y = lrelu(acc + b1s[o]);            // y[o] at lane o (dup at o+32)

        acc = 0.f;
        #pragma unroll
        for (int i = 0; i < 32; ++i)
            acc += __shfl(y, i) * w1s1[o][i];
        float y2 = lrelu(acc + b1s[32 + o]);

        acc = 0.f;
        #pragma unroll
        for (int i = 0; i < 32; ++i)
            acc += __shfl(y2, i) * w1s2[o16][i];
        float t1 = acc + b1s[64 + o16];

        // argmax over 16 (first-index tie-break, matches np.argmax)
        float bv = t1; int bi = o16;
        #pragma unroll
        for (int d = 1; d < 16; d <<= 1) {
            float ov = __shfl_xor(bv, d);
            int   oi = __shfl_xor(bi, d);
            if (ov > bv || (ov == bv && oi < bi)) { bv = ov; bi = oi; }
        }
        const int inds1 = bi;                     // uniform across wave
        const int idx1  = inds1 + 16 * h;

        // ================= stage 2 (CondMul by idx1) =================
        const float* Wp = w2_0 + (size_t)idx1 * (CIN_ * 32);
        acc = 0.f;
        #pragma unroll 8
        for (int i = 0; i < 64; ++i) {
            int ii = half * 64 + i;
            acc += xr[ii] * Wp[ii * 32 + o];      // coalesced over o
        }
        acc += __shfl_xor(acc, 32);
        y = lrelu(acc + b2_0[idx1 * 32 + o]);

        Wp = w2_1 + (size_t)idx1 * (32 * 32);
        acc = 0.f;
        #pragma unroll
        for (int i = 0; i < 32; ++i)
            acc += __shfl(y, i) * Wp[i * 32 + o];
        y2 = lrelu(acc + b2_1[idx1 * 32 + o]);

        Wp = w2_2 + (size_t)idx1 * (32 * 32);
        acc = 0.f;
        #pragma unroll
        for (int i = 0; i < 32; ++i)
            acc += __shfl(y2, i) * Wp[i * 32 + o];
        float y3 = acc + b2_2[idx1 * 32 + o];

        bv = y3; bi = o;
        #pragma unroll
        for (int d = 1; d < 32; d <<= 1) {
            float ov = __shfl_xor(bv, d);
            int   oi = __shfl_xor(bi, d);
            if (ov > bv || (ov == bv && oi < bi)) { bv = ov; bi = oi; }
        }
        const int inds2  = bi;
        const int inds12 = inds1 * 16 + inds2 - 8;          // may be <0 or >255
        const int clip12 = min(max(inds12, 0), 255);
        const int idx12  = clip12 + 256 * h;

        // ================= stage 3 (CondMul by idx12) =================
        Wp = w3_0 + (size_t)idx12 * (CIN_ * 32);
        acc = 0.f;
        #pragma unroll 8
        for (int i = 0; i < 64; ++i) {
            int ii = half * 64 + i;
            acc += xr[ii] * Wp[ii * 32 + o];
        }
        acc += __shfl_xor(acc, 32);
        y = lrelu(acc + b3_0[idx12 * 32 + o]);

        Wp = w3_1 + (size_t)idx12 * (32 * 32);
        acc = 0.f;
        #pragma unroll
        for (int i = 0; i < 32; ++i)
            acc += __shfl(y, i) * Wp[i * 32 + o];
        y2 = lrelu(acc + b3_1[idx12 * 32 + o]);

        Wp = w3_2 + (size_t)idx12 * (32 * 32);
        acc = 0.f;
        #pragma unroll
        for (int i = 0; i < 32; ++i)
            acc += __shfl(y2, i) * Wp[i * 32 + o];
        y3 = acc + b3_2[idx12 * 32 + o];

        bv = y3; bi = o;
        #pragma unroll
        for (int d = 1; d < 32; d <<= 1) {
            float ov = __shfl_xor(bv, d);
            int   oi = __shfl_xor(bi, d);
            if (ov > bv || (ov == bv && oi < bi)) { bv = ov; bi = oi; }
        }
        const int inds3 = bi;
        int inds123 = inds12 * 16 + inds3 - 8;
        inds123 = min(max(inds123, 0), 4095);

        if (lane == 0) out[h * WW + w0 + pix] = inds123;
    }
}

extern "C" void kernel_launch(void* const* d_in, const int* in_sizes, int n_in,
                              void* d_out, int out_size, void* d_ws, size_t ws_size,
                              hipStream_t stream)
{
    const float* x_in = (const float*)d_in[0];
    const float* w1_0 = (const float*)d_in[1];
    const float* b1_0 = (const float*)d_in[2];
    const float* w1_1 = (const float*)d_in[3];
    const float* b1_1 = (const float*)d_in[4];
    const float* w1_2 = (const float*)d_in[5];
    const float* b1_2 = (const float*)d_in[6];
    const float* w2_0 = (const float*)d_in[7];
    const float* b2_0 = (const float*)d_in[8];
    const float* w2_1 = (const float*)d_in[9];
    const float* b2_1 = (const float*)d_in[10];
    const float* w2_2 = (const float*)d_in[11];
    const float* b2_2 = (const float*)d_in[12];
    const float* w3_0 = (const float*)d_in[13];
    const float* b3_0 = (const float*)d_in[14];
    const float* w3_1 = (const float*)d_in[15];
    const float* b3_1 = (const float*)d_in[16];
    const float* w3_2 = (const float*)d_in[17];
    const float* b3_2 = (const float*)d_in[18];
    int* out = (int*)d_out;

    dim3 grid(HH * (WW / TILE));   // 4480 blocks
    reg3_fused<<<grid, 256, 0, stream>>>(
        x_in, w1_0, b1_0, w1_1, b1_1, w1_2, b1_2,
        w2_0, b2_0, w2_1, b2_1, w2_2, b2_2,
        w3_0, b3_0, w3_1, b3_1, w3_2, b3_2, out);
}

// Round 3
// 437.317 us; speedup vs baseline: 1.1396x; 1.1396x over previous
//
#include <hip/hip_runtime.h>

#define HH   112
#define WW   320
#define CIN_ 128
#define TILE 8            // pixels per block; 512 threads = 8 waves, 1 pixel/wave

__device__ __forceinline__ float lrelu(float v) {
    return v >= 0.f ? v : 0.01f * v;
}

__global__ __launch_bounds__(512, 4)
void reg3_fused(const float* __restrict__ x_in,
                const float* __restrict__ w1_0, const float* __restrict__ b1_0,
                const float* __restrict__ w1_1, const float* __restrict__ b1_1,
                const float* __restrict__ w1_2, const float* __restrict__ b1_2,
                const float* __restrict__ w2_0, const float* __restrict__ b2_0,
                const float* __restrict__ w2_1, const float* __restrict__ b2_1,
                const float* __restrict__ w2_2, const float* __restrict__ b2_2,
                const float* __restrict__ w3_0, const float* __restrict__ b3_0,
                const float* __restrict__ w3_1, const float* __restrict__ b3_1,
                const float* __restrict__ w3_2, const float* __restrict__ b3_2,
                int* __restrict__ out)
{
    __shared__ float xT[TILE][CIN_ + 1];
    __shared__ float w1s0[32][CIN_ + 1];
    __shared__ float w1s1[32][33];
    __shared__ float w1s2[16][33];
    __shared__ float b1s[80];

    const int tilesPerLine = WW / TILE;       // 40
    const int h   = blockIdx.x / tilesPerLine;
    const int w0  = (blockIdx.x % tilesPerLine) * TILE;
    const int tid = threadIdx.x;

    for (int n = tid; n < TILE * CIN_; n += 512) {
        int ww = n & 7, c = n >> 3;
        xT[ww][c] = x_in[c * (HH * WW) + h * WW + w0 + ww];
    }
    for (int n = tid; n < 32 * CIN_; n += 512)
        w1s0[n >> 7][n & 127] = w1_0[h * (32 * CIN_) + n];
    for (int n = tid; n < 32 * 32; n += 512)
        w1s1[n >> 5][n & 31] = w1_1[h * (32 * 32) + n];
    if (tid < 16 * 32)
        w1s2[tid >> 5][tid & 31] = w1_2[h * (16 * 32) + tid];
    if      (tid < 32) b1s[tid] = b1_0[h * 32 + tid];
    else if (tid < 64) b1s[tid] = b1_1[h * 32 + (tid - 32)];
    else if (tid < 80) b1s[tid] = b1_2[h * 16 + (tid - 64)];
    __syncthreads();

    const int wave = tid >> 6;                // = pixel within tile
    const int lane = tid & 63;
    const int o    = lane & 31;
    const int half = lane >> 5;
    const int o16  = lane & 15;
    const int pix  = wave;
    const float* xr = &xT[pix][0];

    // ============ stage 1 (per-line weights, LDS) — round-1 exact order ============
    float acc = 0.f;
    #pragma unroll
    for (int i = 0; i < 64; ++i) {
        int ii = half * 64 + i;
        acc += xr[ii] * w1s0[o][ii];
    }
    acc += __shfl_xor(acc, 32);
    float y = lrelu(acc + b1s[o]);            // y[o] at lane o (dup at o+32)

    acc = 0.f;
    #pragma unroll
    for (int i = 0; i < 32; ++i)
        acc += __shfl(y, i) * w1s1[o][i];
    float y2 = lrelu(acc + b1s[32 + o]);

    acc = 0.f;
    #pragma unroll
    for (int i = 0; i < 32; ++i)
        acc += __shfl(y2, i) * w1s2[o16][i];
    float t1 = acc + b1s[64 + o16];

    // argmax over 16 (first-index tie-break, matches np.argmax)
    float bv = t1; int bi = o16;
    #pragma unroll
    for (int d = 1; d < 16; d <<= 1) {
        float ov = __shfl_xor(bv, d);
        int   oi = __shfl_xor(bi, d);
        if (ov > bv || (ov == bv && oi < bi)) { bv = ov; bi = oi; }
    }
    const int inds1 = bi;                     // uniform across wave
    const int idx1  = inds1 + 16 * h;

    // ============ stage 2 (CondMul by idx1) — round-1 order, full unroll ============
    const float* Wp = w2_0 + (size_t)idx1 * (CIN_ * 32);
    acc = 0.f;
    #pragma unroll
    for (int i = 0; i < 64; ++i) {
        int ii = half * 64 + i;
        acc += xr[ii] * Wp[ii * 32 + o];      // coalesced over o
    }
    acc += __shfl_xor(acc, 32);
    y = lrelu(acc + b2_0[idx1 * 32 + o]);

    Wp = w2_1 + (size_t)idx1 * (32 * 32);
    acc = 0.f;
    #pragma unroll
    for (int i = 0; i < 32; ++i)
        acc += __shfl(y, i) * Wp[i * 32 + o];
    y2 = lrelu(acc + b2_1[idx1 * 32 + o]);

    Wp = w2_2 + (size_t)idx1 * (32 * 32);
    acc = 0.f;
    #pragma unroll
    for (int i = 0; i < 32; ++i)
        acc += __shfl(y2, i) * Wp[i * 32 + o];
    float y3 = acc + b2_2[idx1 * 32 + o];

    bv = y3; bi = o;
    #pragma unroll
    for (int d = 1; d < 32; d <<= 1) {
        float ov = __shfl_xor(bv, d);
        int   oi = __shfl_xor(bi, d);
        if (ov > bv || (ov == bv && oi < bi)) { bv = ov; bi = oi; }
    }
    const int inds2  = bi;
    const int inds12 = inds1 * 16 + inds2 - 8;          // may be <0 or >255
    const int clip12 = min(max(inds12, 0), 255);
    const int idx12  = clip12 + 256 * h;

    // ============ stage 3 (CondMul by idx12) — round-1 order, full unroll ============
    Wp = w3_0 + (size_t)idx12 * (CIN_ * 32);
    acc = 0.f;
    #pragma unroll
    for (int i = 0; i < 64; ++i) {
        int ii = half * 64 + i;
        acc += xr[ii] * Wp[ii * 32 + o];
    }
    acc += __shfl_xor(acc, 32);
    y = lrelu(acc + b3_0[idx12 * 32 + o]);

    Wp = w3_1 + (size_t)idx12 * (32 * 32);
    acc = 0.f;
    #pragma unroll
    for (int i = 0; i < 32; ++i)
        acc += __shfl(y, i) * Wp[i * 32 + o];
    y2 = lrelu(acc + b3_1[idx12 * 32 + o]);

    Wp = w3_2 + (size_t)idx12 * (32 * 32);
    acc = 0.f;
    #pragma unroll
    for (int i = 0; i < 32; ++i)
        acc += __shfl(y2, i) * Wp[i * 32 + o];
    y3 = acc + b3_2[idx12 * 32 + o];

    bv = y3; bi = o;
    #pragma unroll
    for (int d = 1; d < 32; d <<= 1) {
        float ov = __shfl_xor(bv, d);
        int   oi = __shfl_xor(bi, d);
        if (ov > bv || (ov == bv && oi < bi)) { bv = ov; bi = oi; }
    }
    const int inds3 = bi;
    int inds123 = inds12 * 16 + inds3 - 8;
    inds123 = min(max(inds123, 0), 4095);

    if (lane == 0) out[h * WW + w0 + pix] = inds123;
}

extern "C" void kernel_launch(void* const* d_in, const int* in_sizes, int n_in,
                              void* d_out, int out_size, void* d_ws, size_t ws_size,
                              hipStream_t stream)
{
    const float* x_in = (const float*)d_in[0];
    const float* w1_0 = (const float*)d_in[1];
    const float* b1_0 = (const float*)d_in[2];
    const float* w1_1 = (const float*)d_in[3];
    const float* b1_1 = (const float*)d_in[4];
    const float* w1_2 = (const float*)d_in[5];
    const float* b1_2 = (const float*)d_in[6];
    const float* w2_0 = (const float*)d_in[7];
    const float* b2_0 = (const float*)d_in[8];
    const float* w2_1 = (const float*)d_in[9];
    const float* b2_1 = (const float*)d_in[10];
    const float* w2_2 = (const float*)d_in[11];
    const float* b2_2 = (const float*)d_in[12];
    const float* w3_0 = (const float*)d_in[13];
    const float* b3_0 = (const float*)d_in[14];
    const float* w3_1 = (const float*)d_in[15];
    const float* b3_1 = (const float*)d_in[16];
    const float* w3_2 = (const float*)d_in[17];
    const float* b3_2 = (const float*)d_in[18];
    int* out = (int*)d_out;

    dim3 grid(HH * (WW / TILE));   // 4480 blocks x 512 threads
    reg3_fused<<<grid, 512, 0, stream>>>(
        x_in, w1_0, b1_0, w1_1, b1_1, w1_2, b1_2,
        w2_0, b2_0, w2_1, b2_1, w2_2, b2_2,
        w3_0, b3_0, w3_1, b3_1, w3_2, b3_2, out);
}